// Round 21
// baseline (1287.913 us; speedup 1.0000x reference)
//
#include <hip/hip_runtime.h>
#include <hip/hip_bf16.h>

#define MFMA_BF16 __builtin_amdgcn_mfma_f32_16x16x32_bf16

typedef __attribute__((ext_vector_type(8))) short short8;
typedef __attribute__((ext_vector_type(4))) float f32x4;

#define NB 16384
#define NH 15
#define NS 32
#define ND 256
#define NHID 256
#define NA 6

// bf16 weight workspace, B-frag tiled layout:
// matrix [N][K] -> tiles t=n/16, kb=k/32; tile = 512 shorts (1KB) in lane order:
//   elem(lane, e) = W[t*16 + (lane&15)][kb*32 + (lane>>4)*8 + e]
// tile offset = OFF + (t*KB + kb)*512,  KB = K/32
#define OFF_A0   0         // N=256 K=288 (32 stoch | 256 gru), KB=9
#define OFF_A1   73728     // N=256 K=256, KB=8
#define OFF_AMS  139264    // N=16  K=256: rows 0..5 W_am, 6..11 W_as, 12..15 zero
#define OFF_IMG  143360    // N=256 K=64 (38 padded), KB=2
#define OFF_IH   159744    // N=768 K=256, KB=8, 48 tiles
#define OFF_HH   356352    // N=768 K=256
#define OFF_P0   552960    // N=256 K=256
#define OFF_PMS  618496    // N=64  K=256: rows 0..31 W_pm, 32..63 W_ps
#define W_TOTAL  634880

__device__ __forceinline__ short f2b(float v){ __hip_bfloat16 b = __float2bfloat16(v); return __builtin_bit_cast(short, b); }
__device__ __forceinline__ float b2f(short s){ return __bfloat162float(__builtin_bit_cast(__hip_bfloat16, s)); }
__device__ __forceinline__ float sigm(float x){ return 1.f/(1.f + __expf(-x)); }
__device__ __forceinline__ float softp(float x){ return fmaxf(x,0.f) + log1pf(__expf(-fabsf(x))); }
__device__ __forceinline__ float eluf(float x){ return x>0.f ? x : (__expf(x)-1.f); }

__device__ __forceinline__ void decode_frag(int m, int KB, int& row, int& k){
  int tidx = m >> 9, w = m & 511;
  int lane = w >> 3, e = w & 7;
  int t = tidx / KB, kb = tidx - t*KB;
  row = t*16 + (lane & 15);
  k   = kb*32 + ((lane >> 4) << 3) + e;
}

__global__ void pack_w(const float* __restrict__ a0, const float* __restrict__ a1,
                       const float* __restrict__ am, const float* __restrict__ as,
                       const float* __restrict__ img, const float* __restrict__ ih,
                       const float* __restrict__ hh, const float* __restrict__ p0,
                       const float* __restrict__ pm, const float* __restrict__ ps,
                       short* __restrict__ ws){
  int i = blockIdx.x*256 + threadIdx.x;
  if (i >= W_TOTAL) return;
  int row, k; float v;
  if (i < OFF_A1){        decode_frag(i - OFF_A0, 9, row, k);  v = a0[row*288 + k]; }
  else if (i < OFF_AMS){  decode_frag(i - OFF_A1, 8, row, k);  v = a1[row*256 + k]; }
  else if (i < OFF_IMG){  decode_frag(i - OFF_AMS, 8, row, k);
                          v = row<6 ? am[row*256+k] : (row<12 ? as[(row-6)*256+k] : 0.f); }
  else if (i < OFF_IH){   decode_frag(i - OFF_IMG, 2, row, k);
                          v = k<38 ? img[row*38 + k] : 0.f; }
  else if (i < OFF_HH){   decode_frag(i - OFF_IH, 8, row, k);  v = ih[row*256 + k]; }
  else if (i < OFF_P0){   decode_frag(i - OFF_HH, 8, row, k);  v = hh[row*256 + k]; }
  else if (i < OFF_PMS){  decode_frag(i - OFF_P0, 8, row, k);  v = p0[row*256 + k]; }
  else {                  decode_frag(i - OFF_PMS, 8, row, k);
                          v = row<32 ? pm[row*256+k] : ps[(row-32)*256+k]; }
  ws[i] = f2b(v);
}

// N=256 layer: A[32][K](LDS) @ W^T + bias (+elu) -> O cols [wid*64 .. wid*64+63].
// Fused: acc[2 mt][4 j] = 32 regs (r5's proven shape at VGPR=128);
// 4 independent B-load streams per kb for ILP.
template<int KB, bool ELU>
__device__ __forceinline__ void dense_full(const short* __restrict__ Ab, int astr,
                                           const short* __restrict__ W,
                                           const float* __restrict__ bias,
                                           short* __restrict__ Ob,
                                           int tbase, int n0, int lane, int lk){
  f32x4 acc[2][4] = {};
  const short* ap = Ab + (lane & 15)*astr + lk*8;
  const int astep = 16*astr;
  const short* wl = W + lane*8;
  #pragma unroll
  for (int kb=0; kb<KB; ++kb){
    short8 a0 = *(const short8*)(ap + kb*32);
    short8 a1 = *(const short8*)(ap + astep + kb*32);
    #pragma unroll
    for (int j=0; j<4; ++j){
      short8 b = *(const short8*)(wl + ((tbase + j)*KB + kb)*512);
      acc[0][j] = MFMA_BF16(a0, b, acc[0][j], 0, 0, 0);
      acc[1][j] = MFMA_BF16(a1, b, acc[1][j], 0, 0, 0);
    }
  }
  #pragma unroll
  for (int mt=0; mt<2; ++mt){
    #pragma unroll
    for (int j=0; j<4; ++j){
      int n = n0 + j*16;
      float bs = bias[n];
      #pragma unroll
      for (int i=0; i<4; ++i){
        int row = mt*16 + lk*4 + i;
        float v = acc[mt][j][i] + bs;
        Ob[row*264 + n] = f2b(ELU ? eluf(v) : v);
      }
    }
  }
}

__global__ __launch_bounds__(256, 2) void dream_kernel(
    const float* __restrict__ stoch0, const float* __restrict__ gru0,
    const float* __restrict__ anoise, const float* __restrict__ snoise,
    const short* __restrict__ ws,
    const float* __restrict__ b_a0, const float* __restrict__ b_a1,
    const float* __restrict__ b_am, const float* __restrict__ b_as,
    const float* __restrict__ b_img, const float* __restrict__ b_ih,
    const float* __restrict__ b_hh, const float* __restrict__ b_p0,
    const float* __restrict__ b_pm, const float* __restrict__ b_ps,
    float* __restrict__ out)
{
  __shared__ short bufA[32*264];
  __shared__ short bufB[32*264];
  __shared__ short bufC[32*264];
  __shared__ short simg[32*72];   // cols 0..31 stoch, 32..37 action, 38..63 zero

  const int tid   = threadIdx.x;
  const int wid   = tid >> 6;            // 0..3
  const int lane  = tid & 63;
  const int lrow  = lane & 15;
  const int lk    = lane >> 4;
  const int r0    = blockIdx.x * 32;
  const int tbase = wid * 4;             // 4 B n-tiles per wave
  const int n0    = wid * 64 + lrow;     // output column base (lane-dependent)

  for (int idx = tid; idx < 32*256; idx += 256){
    int r = idx >> 8, c = idx & 255;
    bufA[r*264 + c] = f2b(gru0[(size_t)(r0+r)*256 + c]);
  }
  for (int idx = tid; idx < 32*32; idx += 256){
    int r = idx >> 5, c = idx & 31;
    simg[r*72 + c]      = f2b(stoch0[(size_t)(r0+r)*32 + c]);
    simg[r*72 + 32 + c] = 0;
  }
  __syncthreads();

  short* G = bufA;   // gru state h
  short* X = bufB;   // scratch
  short* Y = bufC;   // scratch; holds h_new after GRU

  for (int h = 0; h < NH; ++h){
    // ---- a0: elu([stoch|gru] @ W_a0^T + b), K=288 (kb0 simg, kb1..8 G) -> X
    {
      f32x4 acc[2][4] = {};
      const short* ai = simg + lrow*72  + lk*8;
      const short* ag = G    + lrow*264 + lk*8;
      const short* wl = ws + OFF_A0 + lane*8;
      #pragma unroll
      for (int kb=0; kb<9; ++kb){
        short8 a0 = (kb==0) ? *(const short8*)ai : *(const short8*)(ag + (kb-1)*32);
        short8 a1 = (kb==0) ? *(const short8*)(ai + 16*72) : *(const short8*)(ag + 16*264 + (kb-1)*32);
        #pragma unroll
        for (int j=0; j<4; ++j){
          short8 b = *(const short8*)(wl + ((tbase + j)*9 + kb)*512);
          acc[0][j] = MFMA_BF16(a0, b, acc[0][j], 0, 0, 0);
          acc[1][j] = MFMA_BF16(a1, b, acc[1][j], 0, 0, 0);
        }
      }
      #pragma unroll
      for (int mt=0; mt<2; ++mt)
        #pragma unroll
        for (int j=0; j<4; ++j){
          int n = n0 + j*16;
          float bs = b_a0[n];
          #pragma unroll
          for (int i=0; i<4; ++i){
            int row = mt*16 + lk*4 + i;
            X[row*264 + n] = f2b(eluf(acc[mt][j][i] + bs));
          }
        }
    }
    __syncthreads();

    // ---- a1: elu(X @ W_a1^T + b) -> Y
    dense_full<8,true>(X, 264, ws + OFF_A1, b_a1, Y, tbase, n0, lane, lk);
    __syncthreads();

    // ---- am/as: Y @ [W_am;W_as]^T -> action into simg cols 32..37
    if (wid < 2){
      const int mt = wid;
      f32x4 acc = {};
      const short* ap = Y + (mt*16+lrow)*264 + lk*8;
      const short* wl = ws + OFF_AMS + lane*8;
      #pragma unroll
      for (int kb=0; kb<8; ++kb){
        short8 a = *(const short8*)(ap + kb*32);
        short8 b = *(const short8*)(wl + kb*512);
        acc = MFMA_BF16(a, b, acc, 0, 0, 0);
      }
      float bs = (lrow<6) ? b_am[lrow] : (lrow<12 ? b_as[lrow-6] : 0.f);
      #pragma unroll
      for (int i=0; i<4; ++i){
        float raw = acc[i] + bs;
        float sp  = softp(raw);
        float spn = __shfl(sp, (lane & 48) | ((lrow + 6) & 15));
        if (lrow < 6){
          int row = mt*16 + lk*4 + i;
          size_t grow = r0 + row;
          float an = __builtin_nontemporal_load(&anoise[((size_t)h*NB + grow)*NA + lrow]);
          simg[row*72 + 32 + lrow] = f2b(raw + spn * an);
        }
      }
    }
    __syncthreads();

    // ---- img: elu([stoch|action|0] @ W_img^T + b), K=64 -> X
    dense_full<2,true>(simg, 72, ws + OFF_IMG, b_img, X, tbase, n0, lane, lk);
    __syncthreads();

    // ---- GRU: mtl- and jj-sequential (lean). reads X (img), G (h_old);
    // writes h_new -> Y + NT out store. Wave owns 4 col-tiles.
    {
      const short* wl_ih = ws + OFF_IH + lane*8;
      const short* wl_hh = ws + OFF_HH + lane*8;
      #pragma unroll 1
      for (int mtl=0; mtl<2; ++mtl){
        const int rbase = mtl*16;
        const short* xp = X + (rbase+lrow)*264 + lk*8;
        const short* gp = G + (rbase+lrow)*264 + lk*8;
        #pragma unroll 1
        for (int jj=0; jj<4; ++jj){
          f32x4 aR = {}, aZ = {}, aI = {}, aH = {};
          const int tr = wid*4 + jj;
          #pragma unroll
          for (int kb=0; kb<8; ++kb){
            short8 br = *(const short8*)(wl_ih + ((tr     )*8 + kb)*512);
            short8 bz = *(const short8*)(wl_ih + ((tr + 16)*8 + kb)*512);
            short8 bn = *(const short8*)(wl_ih + ((tr + 32)*8 + kb)*512);
            short8 cr = *(const short8*)(wl_hh + ((tr     )*8 + kb)*512);
            short8 cz = *(const short8*)(wl_hh + ((tr + 16)*8 + kb)*512);
            short8 ch = *(const short8*)(wl_hh + ((tr + 32)*8 + kb)*512);
            short8 ax = *(const short8*)(xp + kb*32);
            short8 ag = *(const short8*)(gp + kb*32);
            aR = MFMA_BF16(ax, br, aR, 0, 0, 0);
            aZ = MFMA_BF16(ax, bz, aZ, 0, 0, 0);
            aI = MFMA_BF16(ax, bn, aI, 0, 0, 0);
            aR = MFMA_BF16(ag, cr, aR, 0, 0, 0);
            aZ = MFMA_BF16(ag, cz, aZ, 0, 0, 0);
            aH = MFMA_BF16(ag, ch, aH, 0, 0, 0);
          }
          int c = wid*64 + jj*16 + lrow;
          float bir = b_ih[c]       + b_hh[c];
          float biz = b_ih[256 + c] + b_hh[256 + c];
          float bin = b_ih[512 + c];
          float bhn = b_hh[512 + c];
          #pragma unroll
          for (int i=0; i<4; ++i){
            int row = rbase + lk*4 + i;
            float hold = b2f(G[row*264 + c]);
            float r = sigm(aR[i] + bir);
            float z = sigm(aZ[i] + biz);
            float n = tanhf(aI[i] + bin + r*(aH[i] + bhn));
            float hnew = (1.f - z)*n + z*hold;
            Y[row*264 + c] = f2b(hnew);
            __builtin_nontemporal_store(hnew, &out[((size_t)h*NB + (size_t)(r0+row))*288 + 32 + c]);
          }
        }
      }
    }
    __syncthreads();

    // ---- p0: elu(Y(h_new) @ W_p0^T + b) -> X
    dense_full<8,true>(Y, 264, ws + OFF_P0, b_p0, X, tbase, n0, lane, lk);
    __syncthreads();

    // ---- pm/ps: X @ [W_pm;W_ps]^T -> stoch into simg + NT out (all 4 waves)
    {
      const int mt = wid & 1;
      const int jp = wid >> 1;
      f32x4 accM = {}, accS = {};
      const short* ap = X + (mt*16+lrow)*264 + lk*8;
      const short* wl = ws + OFF_PMS + lane*8;
      #pragma unroll
      for (int kb=0; kb<8; ++kb){
        short8 a  = *(const short8*)(ap + kb*32);
        short8 bm = *(const short8*)(wl + ((jp    )*8 + kb)*512);
        short8 bs = *(const short8*)(wl + ((jp + 2)*8 + kb)*512);
        accM = MFMA_BF16(a, bm, accM, 0, 0, 0);
        accS = MFMA_BF16(a, bs, accS, 0, 0, 0);
      }
      int sc = jp*16 + lrow;
      float bm = b_pm[sc], bp = b_ps[sc];
      #pragma unroll
      for (int i=0; i<4; ++i){
        int row = mt*16 + lk*4 + i;
        size_t grow = r0 + row;
        float m  = accM[i] + bm;
        float sp = softp(accS[i] + bp);
        float sn = __builtin_nontemporal_load(&snoise[((size_t)h*NB + grow)*NS + sc]);
        float st = m + sp*sn;
        simg[row*72 + sc] = f2b(st);
        __builtin_nontemporal_store(st, &out[((size_t)h*NB + grow)*288 + sc]);
      }
    }
    __syncthreads();

    // rotate: h := Y; old G and X become scratch
    short* t = G; G = Y; Y = X; X = t;
  }
}

extern "C" void kernel_launch(void* const* d_in, const int* in_sizes, int n_in,
                              void* d_out, int out_size, void* d_ws, size_t ws_size,
                              hipStream_t stream){
  const float* stoch0 = (const float*)d_in[0];
  const float* gru0   = (const float*)d_in[1];
  const float* anoise = (const float*)d_in[2];
  const float* snoise = (const float*)d_in[3];
  const float* Wa0 = (const float*)d_in[4];   const float* ba0 = (const float*)d_in[5];
  const float* Wa1 = (const float*)d_in[6];   const float* ba1 = (const float*)d_in[7];
  const float* Wam = (const float*)d_in[8];   const float* bam = (const float*)d_in[9];
  const float* Was = (const float*)d_in[10];  const float* bas = (const float*)d_in[11];
  const float* Wimg= (const float*)d_in[12];  const float* bimg= (const float*)d_in[13];
  const float* Wih = (const float*)d_in[14];  const float* bih = (const float*)d_in[15];
  const float* Whh = (const float*)d_in[16];  const float* bhh = (const float*)d_in[17];
  const float* Wp0 = (const float*)d_in[18];  const float* bp0 = (const float*)d_in[19];
  const float* Wpm = (const float*)d_in[20];  const float* bpm = (const float*)d_in[21];
  const float* Wps = (const float*)d_in[22];  const float* bps = (const float*)d_in[23];
  short* ws  = (short*)d_ws;
  float* out = (float*)d_out;

  pack_w<<<(W_TOTAL + 255)/256, 256, 0, stream>>>(Wa0, Wa1, Wam, Was, Wimg, Wih, Whh, Wp0, Wpm, Wps, ws);
  dream_kernel<<<NB/32, 256, 0, stream>>>(stoch0, gru0, anoise, snoise, ws,
                                          ba0, ba1, bam, bas, bimg, bih, bhh, bp0, bpm, bps, out);
}

// Round 22
// 1084.352 us; speedup vs baseline: 1.1877x; 1.1877x over previous
//
#include <hip/hip_runtime.h>
#include <hip/hip_bf16.h>

#define MFMA_BF16 __builtin_amdgcn_mfma_f32_16x16x32_bf16

typedef __attribute__((ext_vector_type(8))) short short8;
typedef __attribute__((ext_vector_type(4))) float f32x4;

#define NB 16384
#define NH 15
#define NS 32
#define ND 256
#define NHID 256
#define NA 6

// bf16 weight workspace, B-frag tiled layout:
// matrix [N][K] -> tiles t=n/16, kb=k/32; tile = 512 shorts (1KB) in lane order:
//   elem(lane, e) = W[t*16 + (lane&15)][kb*32 + (lane>>4)*8 + e]
// tile offset = OFF + (t*KB + kb)*512,  KB = K/32
#define OFF_A0   0         // N=256 K=288 (32 stoch | 256 gru), KB=9
#define OFF_A1   73728     // N=256 K=256, KB=8
#define OFF_AMS  139264    // N=16  K=256: rows 0..5 W_am, 6..11 W_as, 12..15 zero
#define OFF_IMG  143360    // N=256 K=64 (38 padded), KB=2
#define OFF_IH   159744    // N=768 K=256, KB=8, 48 tiles
#define OFF_HH   356352    // N=768 K=256
#define OFF_P0   552960    // N=256 K=256
#define OFF_PMS  618496    // N=64  K=256: rows 0..31 W_pm, 32..63 W_ps
#define W_TOTAL  634880

__device__ __forceinline__ short f2b(float v){ __hip_bfloat16 b = __float2bfloat16(v); return __builtin_bit_cast(short, b); }
__device__ __forceinline__ float b2f(short s){ return __bfloat162float(__builtin_bit_cast(__hip_bfloat16, s)); }
__device__ __forceinline__ float sigm(float x){ return 1.f/(1.f + __expf(-x)); }
__device__ __forceinline__ float softp(float x){ return fmaxf(x,0.f) + log1pf(__expf(-fabsf(x))); }
__device__ __forceinline__ float eluf(float x){ return x>0.f ? x : (__expf(x)-1.f); }

__device__ __forceinline__ void decode_frag(int m, int KB, int& row, int& k){
  int tidx = m >> 9, w = m & 511;
  int lane = w >> 3, e = w & 7;
  int t = tidx / KB, kb = tidx - t*KB;
  row = t*16 + (lane & 15);
  k   = kb*32 + ((lane >> 4) << 3) + e;
}

__global__ void pack_w(const float* __restrict__ a0, const float* __restrict__ a1,
                       const float* __restrict__ am, const float* __restrict__ as,
                       const float* __restrict__ img, const float* __restrict__ ih,
                       const float* __restrict__ hh, const float* __restrict__ p0,
                       const float* __restrict__ pm, const float* __restrict__ ps,
                       short* __restrict__ ws){
  int i = blockIdx.x*256 + threadIdx.x;
  if (i >= W_TOTAL) return;
  int row, k; float v;
  if (i < OFF_A1){        decode_frag(i - OFF_A0, 9, row, k);  v = a0[row*288 + k]; }
  else if (i < OFF_AMS){  decode_frag(i - OFF_A1, 8, row, k);  v = a1[row*256 + k]; }
  else if (i < OFF_IMG){  decode_frag(i - OFF_AMS, 8, row, k);
                          v = row<6 ? am[row*256+k] : (row<12 ? as[(row-6)*256+k] : 0.f); }
  else if (i < OFF_IH){   decode_frag(i - OFF_IMG, 2, row, k);
                          v = k<38 ? img[row*38 + k] : 0.f; }
  else if (i < OFF_HH){   decode_frag(i - OFF_IH, 8, row, k);  v = ih[row*256 + k]; }
  else if (i < OFF_P0){   decode_frag(i - OFF_HH, 8, row, k);  v = hh[row*256 + k]; }
  else if (i < OFF_PMS){  decode_frag(i - OFF_P0, 8, row, k);  v = p0[row*256 + k]; }
  else {                  decode_frag(i - OFF_PMS, 8, row, k);
                          v = row<32 ? pm[row*256+k] : ps[(row-32)*256+k]; }
  ws[i] = f2b(v);
}

// N=256 layer half-slice: A[32][K](LDS) @ W^T + bias (+elu) -> O cols [n0..n0+31].
// Lean: acc[2 mt][2 j] (~40 regs). Called twice per wave (two n-halves).
template<int KB, bool ELU>
__device__ __forceinline__ void dense_slice(const short* __restrict__ Ab, int astr,
                                            const short* __restrict__ W,
                                            const float* __restrict__ bias,
                                            short* __restrict__ Ob,
                                            int tbase, int n0, int lane, int lk){
  f32x4 acc[2][2] = {};
  const short* ap = Ab + (lane & 15)*astr + lk*8;
  const int astep = 16*astr;
  const short* wl = W + lane*8;
  #pragma unroll
  for (int kb=0; kb<KB; ++kb){
    short8 a0 = *(const short8*)(ap + kb*32);
    short8 a1 = *(const short8*)(ap + astep + kb*32);
    #pragma unroll
    for (int j=0; j<2; ++j){
      short8 b = *(const short8*)(wl + ((tbase + j)*KB + kb)*512);
      acc[0][j] = MFMA_BF16(a0, b, acc[0][j], 0, 0, 0);
      acc[1][j] = MFMA_BF16(a1, b, acc[1][j], 0, 0, 0);
    }
  }
  #pragma unroll
  for (int mt=0; mt<2; ++mt){
    #pragma unroll
    for (int j=0; j<2; ++j){
      int n = n0 + j*16;
      float bs = bias[n];
      #pragma unroll
      for (int i=0; i<4; ++i){
        int row = mt*16 + lk*4 + i;
        float v = acc[mt][j][i] + bs;
        Ob[row*264 + n] = f2b(ELU ? eluf(v) : v);
      }
    }
  }
}

__global__ __launch_bounds__(256, 2) void dream_kernel(
    const float* __restrict__ stoch0, const float* __restrict__ gru0,
    const float* __restrict__ anoise, const float* __restrict__ snoise,
    const short* __restrict__ ws,
    const float* __restrict__ b_a0, const float* __restrict__ b_a1,
    const float* __restrict__ b_am, const float* __restrict__ b_as,
    const float* __restrict__ b_img, const float* __restrict__ b_ih,
    const float* __restrict__ b_hh, const float* __restrict__ b_p0,
    const float* __restrict__ b_pm, const float* __restrict__ b_ps,
    float* __restrict__ out)
{
  __shared__ short bufA[32*264];
  __shared__ short bufB[32*264];
  __shared__ short bufC[32*264];
  __shared__ short simg[32*72];   // cols 0..31 stoch, 32..37 action, 38..63 zero

  const int tid   = threadIdx.x;
  const int wid   = tid >> 6;            // 0..3
  const int lane  = tid & 63;
  const int lrow  = lane & 15;
  const int lk    = lane >> 4;
  const int r0    = blockIdx.x * 32;
  // per-wave n ownership: 64 cols = tiles [wid*4 .. wid*4+3], two lean halves
  const int tb0   = wid * 4;             // half 0 tile base
  const int n00   = wid * 64 + lrow;     // half 0 col base
  const int tb1   = wid * 4 + 2;         // half 1 tile base
  const int n01   = wid * 64 + 32 + lrow;

  for (int idx = tid; idx < 32*256; idx += 256){
    int r = idx >> 8, c = idx & 255;
    bufA[r*264 + c] = f2b(gru0[(size_t)(r0+r)*256 + c]);
  }
  for (int idx = tid; idx < 32*32; idx += 256){
    int r = idx >> 5, c = idx & 31;
    simg[r*72 + c]      = f2b(stoch0[(size_t)(r0+r)*32 + c]);
    simg[r*72 + 32 + c] = 0;
  }
  __syncthreads();

  short* G = bufA;   // gru state h
  short* X = bufB;   // scratch
  short* Y = bufC;   // scratch; holds h_new after GRU

  for (int h = 0; h < NH; ++h){
    // ---- a0: elu([stoch|gru] @ W_a0^T + b), K=288 (kb0 simg, kb1..8 G) -> X
    #pragma unroll 1
    for (int half=0; half<2; ++half){
      const int tbase = half ? tb1 : tb0;
      const int n0    = half ? n01 : n00;
      f32x4 acc[2][2] = {};
      const short* ai = simg + lrow*72  + lk*8;
      const short* ag = G    + lrow*264 + lk*8;
      const short* wl = ws + OFF_A0 + lane*8;
      #pragma unroll
      for (int kb=0; kb<9; ++kb){
        short8 a0 = (kb==0) ? *(const short8*)ai : *(const short8*)(ag + (kb-1)*32);
        short8 a1 = (kb==0) ? *(const short8*)(ai + 16*72) : *(const short8*)(ag + 16*264 + (kb-1)*32);
        #pragma unroll
        for (int j=0; j<2; ++j){
          short8 b = *(const short8*)(wl + ((tbase + j)*9 + kb)*512);
          acc[0][j] = MFMA_BF16(a0, b, acc[0][j], 0, 0, 0);
          acc[1][j] = MFMA_BF16(a1, b, acc[1][j], 0, 0, 0);
        }
      }
      #pragma unroll
      for (int mt=0; mt<2; ++mt)
        #pragma unroll
        for (int j=0; j<2; ++j){
          int n = n0 + j*16;
          float bs = b_a0[n];
          #pragma unroll
          for (int i=0; i<4; ++i){
            int row = mt*16 + lk*4 + i;
            X[row*264 + n] = f2b(eluf(acc[mt][j][i] + bs));
          }
        }
    }
    __syncthreads();

    // ---- a1: elu(X @ W_a1^T + b) -> Y (two lean half-passes)
    dense_slice<8,true>(X, 264, ws + OFF_A1, b_a1, Y, tb0, n00, lane, lk);
    dense_slice<8,true>(X, 264, ws + OFF_A1, b_a1, Y, tb1, n01, lane, lk);
    __syncthreads();

    // ---- merged phase: img kb0 partial (ALL waves, reads stable simg stoch
    // cols 0..31) overlapped with am/as (waves 0,1 -> simg cols 32..37)
    f32x4 iacc[2][2][2];   // [half][mt][j] — held across the barrier
    {
      const short* wlI = ws + OFF_IMG + lane*8;
      const short* ai  = simg + lrow*72 + lk*8;   // kb0: k = lk*8 in 0..31
      #pragma unroll
      for (int half=0; half<2; ++half){
        const int tbs = half ? tb1 : tb0;
        #pragma unroll
        for (int mt=0; mt<2; ++mt){
          short8 a = *(const short8*)(ai + mt*16*72);
          #pragma unroll
          for (int j=0; j<2; ++j){
            short8 b = *(const short8*)(wlI + ((tbs + j)*2 + 0)*512);
            f32x4 z = {};
            iacc[half][mt][j] = MFMA_BF16(a, b, z, 0, 0, 0);
          }
        }
      }
      if (wid < 2){
        const int mt = wid;
        f32x4 acc = {};
        const short* ap = Y + (mt*16+lrow)*264 + lk*8;
        const short* wl = ws + OFF_AMS + lane*8;
        #pragma unroll
        for (int kb=0; kb<8; ++kb){
          short8 a = *(const short8*)(ap + kb*32);
          short8 b = *(const short8*)(wl + kb*512);
          acc = MFMA_BF16(a, b, acc, 0, 0, 0);
        }
        float bs = (lrow<6) ? b_am[lrow] : (lrow<12 ? b_as[lrow-6] : 0.f);
        #pragma unroll
        for (int i=0; i<4; ++i){
          float raw = acc[i] + bs;
          float sp  = softp(raw);
          float spn = __shfl(sp, (lane & 48) | ((lrow + 6) & 15));
          if (lrow < 6){
            int row = mt*16 + lk*4 + i;
            size_t grow = r0 + row;
            float an = __builtin_nontemporal_load(&anoise[((size_t)h*NB + grow)*NA + lrow]);
            simg[row*72 + 32 + lrow] = f2b(raw + spn * an);
          }
        }
      }
    }
    __syncthreads();

    // ---- img finish: kb1 (action cols 32..63) + epilogue -> X
    {
      const short* wlI = ws + OFF_IMG + lane*8;
      const short* ai  = simg + lrow*72 + 32 + lk*8;   // kb1: k = 32 + lk*8
      #pragma unroll
      for (int half=0; half<2; ++half){
        const int tbs = half ? tb1 : tb0;
        #pragma unroll
        for (int mt=0; mt<2; ++mt){
          short8 a = *(const short8*)(ai + mt*16*72);
          #pragma unroll
          for (int j=0; j<2; ++j){
            short8 b = *(const short8*)(wlI + ((tbs + j)*2 + 1)*512);
            iacc[half][mt][j] = MFMA_BF16(a, b, iacc[half][mt][j], 0, 0, 0);
          }
        }
      }
      #pragma unroll
      for (int half=0; half<2; ++half){
        const int nb = half ? n01 : n00;
        #pragma unroll
        for (int mt=0; mt<2; ++mt)
          #pragma unroll
          for (int j=0; j<2; ++j){
            int n = nb + j*16;
            float bs = b_img[n];
            #pragma unroll
            for (int i=0; i<4; ++i){
              int row = mt*16 + lk*4 + i;
              X[row*264 + n] = f2b(eluf(iacc[half][mt][j][i] + bs));
            }
          }
      }
    }
    __syncthreads();

    // ---- GRU: mtl- and jj-sequential (lean). reads X (img), G (h_old);
    // writes h_new -> Y + NT out store. Wave owns 4 col-tiles.
    {
      const short* wl_ih = ws + OFF_IH + lane*8;
      const short* wl_hh = ws + OFF_HH + lane*8;
      #pragma unroll 1
      for (int mtl=0; mtl<2; ++mtl){
        const int rbase = mtl*16;
        const short* xp = X + (rbase+lrow)*264 + lk*8;
        const short* gp = G + (rbase+lrow)*264 + lk*8;
        #pragma unroll 1
        for (int jj=0; jj<4; ++jj){
          f32x4 aR = {}, aZ = {}, aI = {}, aH = {};
          const int tr = wid*4 + jj;
          #pragma unroll
          for (int kb=0; kb<8; ++kb){
            short8 br = *(const short8*)(wl_ih + ((tr     )*8 + kb)*512);
            short8 bz = *(const short8*)(wl_ih + ((tr + 16)*8 + kb)*512);
            short8 bn = *(const short8*)(wl_ih + ((tr + 32)*8 + kb)*512);
            short8 cr = *(const short8*)(wl_hh + ((tr     )*8 + kb)*512);
            short8 cz = *(const short8*)(wl_hh + ((tr + 16)*8 + kb)*512);
            short8 ch = *(const short8*)(wl_hh + ((tr + 32)*8 + kb)*512);
            short8 ax = *(const short8*)(xp + kb*32);
            short8 ag = *(const short8*)(gp + kb*32);
            aR = MFMA_BF16(ax, br, aR, 0, 0, 0);
            aZ = MFMA_BF16(ax, bz, aZ, 0, 0, 0);
            aI = MFMA_BF16(ax, bn, aI, 0, 0, 0);
            aR = MFMA_BF16(ag, cr, aR, 0, 0, 0);
            aZ = MFMA_BF16(ag, cz, aZ, 0, 0, 0);
            aH = MFMA_BF16(ag, ch, aH, 0, 0, 0);
          }
          int c = wid*64 + jj*16 + lrow;
          float bir = b_ih[c]       + b_hh[c];
          float biz = b_ih[256 + c] + b_hh[256 + c];
          float bin = b_ih[512 + c];
          float bhn = b_hh[512 + c];
          #pragma unroll
          for (int i=0; i<4; ++i){
            int row = rbase + lk*4 + i;
            float hold = b2f(G[row*264 + c]);
            float r = sigm(aR[i] + bir);
            float z = sigm(aZ[i] + biz);
            float n = tanhf(aI[i] + bin + r*(aH[i] + bhn));
            float hnew = (1.f - z)*n + z*hold;
            Y[row*264 + c] = f2b(hnew);
            __builtin_nontemporal_store(hnew, &out[((size_t)h*NB + (size_t)(r0+row))*288 + 32 + c]);
          }
        }
      }
    }
    __syncthreads();

    // ---- p0: elu(Y(h_new) @ W_p0^T + b) -> X
    dense_slice<8,true>(Y, 264, ws + OFF_P0, b_p0, X, tb0, n00, lane, lk);
    dense_slice<8,true>(Y, 264, ws + OFF_P0, b_p0, X, tb1, n01, lane, lk);
    __syncthreads();

    // ---- pm/ps: X @ [W_pm;W_ps]^T -> stoch into simg + NT out (all 4 waves)
    {
      const int mt = wid & 1;
      const int jp = wid >> 1;
      f32x4 accM = {}, accS = {};
      const short* ap = X + (mt*16+lrow)*264 + lk*8;
      const short* wl = ws + OFF_PMS + lane*8;
      #pragma unroll
      for (int kb=0; kb<8; ++kb){
        short8 a  = *(const short8*)(ap + kb*32);
        short8 bm = *(const short8*)(wl + ((jp    )*8 + kb)*512);
        short8 bs = *(const short8*)(wl + ((jp + 2)*8 + kb)*512);
        accM = MFMA_BF16(a, bm, accM, 0, 0, 0);
        accS = MFMA_BF16(a, bs, accS, 0, 0, 0);
      }
      int sc = jp*16 + lrow;
      float bm = b_pm[sc], bp = b_ps[sc];
      #pragma unroll
      for (int i=0; i<4; ++i){
        int row = mt*16 + lk*4 + i;
        size_t grow = r0 + row;
        float m  = accM[i] + bm;
        float sp = softp(accS[i] + bp);
        float sn = __builtin_nontemporal_load(&snoise[((size_t)h*NB + grow)*NS + sc]);
        float st = m + sp*sn;
        simg[row*72 + sc] = f2b(st);
        __builtin_nontemporal_store(st, &out[((size_t)h*NB + grow)*288 + sc]);
      }
    }
    __syncthreads();

    // rotate: h := Y; old G and X become scratch
    short* t = G; G = Y; Y = X; X = t;
  }
}

extern "C" void kernel_launch(void* const* d_in, const int* in_sizes, int n_in,
                              void* d_out, int out_size, void* d_ws, size_t ws_size,
                              hipStream_t stream){
  const float* stoch0 = (const float*)d_in[0];
  const float* gru0   = (const float*)d_in[1];
  const float* anoise = (const float*)d_in[2];
  const float* snoise = (const float*)d_in[3];
  const float* Wa0 = (const float*)d_in[4];   const float* ba0 = (const float*)d_in[5];
  const float* Wa1 = (const float*)d_in[6];   const float* ba1 = (const float*)d_in[7];
  const float* Wam = (const float*)d_in[8];   const float* bam = (const float*)d_in[9];
  const float* Was = (const float*)d_in[10];  const float* bas = (const float*)d_in[11];
  const float* Wimg= (const float*)d_in[12];  const float* bimg= (const float*)d_in[13];
  const float* Wih = (const float*)d_in[14];  const float* bih = (const float*)d_in[15];
  const float* Whh = (const float*)d_in[16];  const float* bhh = (const float*)d_in[17];
  const float* Wp0 = (const float*)d_in[18];  const float* bp0 = (const float*)d_in[19];
  const float* Wpm = (const float*)d_in[20];  const float* bpm = (const float*)d_in[21];
  const float* Wps = (const float*)d_in[22];  const float* bps = (const float*)d_in[23];
  short* ws  = (short*)d_ws;
  float* out = (float*)d_out;

  pack_w<<<(W_TOTAL + 255)/256, 256, 0, stream>>>(Wa0, Wa1, Wam, Was, Wimg, Wih, Whh, Wp0, Wpm, Wps, ws);
  dream_kernel<<<NB/32, 256, 0, stream>>>(stoch0, gru0, anoise, snoise, ws,
                                          ba0, ba1, bam, bas, bimg, bih, bhh, bp0, bpm, bps, out);
}